// Round 3
// baseline (231.272 us; speedup 1.0000x reference)
//
#include <hip/hip_runtime.h>
#include <cstdint>

typedef short bf16x8 __attribute__((ext_vector_type(8)));
typedef float f32x4 __attribute__((ext_vector_type(4)));

#define MFMA16(a, b, c) __builtin_amdgcn_mfma_f32_16x16x32_bf16((a), (b), (c), 0, 0, 0)

__device__ __forceinline__ unsigned short f2b(float f) {
  union { float f; unsigned int u; } x; x.f = f;
  unsigned int r = x.u + 0x7fffu + ((x.u >> 16) & 1u);
  return (unsigned short)(r >> 16);
}

__device__ __forceinline__ unsigned int pack2(float lo, float hi) {
  union { float f; unsigned int u; } a, b;
  a.f = lo; b.f = hi;
  return ((a.u + 0x8000u) >> 16) | ((b.u + 0x8000u) & 0xffff0000u);
}

// async global->LDS, 16B per lane, LDS dst = wave-uniform base + lane*16
__device__ __forceinline__ void gl_lds16(const unsigned short* g, unsigned short* l) {
  __builtin_amdgcn_global_load_lds(
      (const __attribute__((address_space(1))) unsigned int*)g,
      (__attribute__((address_space(3))) unsigned int*)l, 16, 0, 0);
}

#define NB 2
#define NS 2048
#define ND 768
#define NH 12
#define DHD 64
#define MTOK 4096  // NB*NS

// ws element offsets (ushort units)
#define OFF_XB 0
#define OFF_WB 3145728   // 5 x 589824 converted weights
#define OFF_QK 6094848   // 4 x 3145728 : Qr,Qi,Kr,Ki  [4096][768]
#define OFF_VT 18677760  // Vt [2][12][64][2048]
#define OFF_PO 21823488  // split-K partial O: 2*24*32*4096 floats
#define OFF_PL 34406400  // split-K partial l: 2*24*32*64 floats (= OFF_PO + 12582912)
#define WS_NEED_SPLIT ((size_t)(OFF_PL + 196608) * 2)  // 69,206,016 B

// one merged conversion kernel: X then 5 weights (Wqr,Wqi scaled)
__global__ void cvt_all(const float* __restrict__ X,
                        const float* __restrict__ W0, const float* __restrict__ W1,
                        const float* __restrict__ W2, const float* __restrict__ W3,
                        const float* __restrict__ W4,
                        unsigned short* __restrict__ Xb,
                        unsigned short* __restrict__ Wb, float qscale) {
  int i = blockIdx.x * blockDim.x + threadIdx.x;  // 1523712 total float4s
  const float* src;
  unsigned short* dst;
  float sc = 1.0f;
  int idx;
  if (i < 786432) {
    src = X; dst = Xb; idx = i;
  } else {
    int j = i - 786432;
    int z = j / 147456;
    idx = j - z * 147456;
    dst = Wb + z * 589824;
    src = (z == 0) ? W0 : (z == 1) ? W1 : (z == 2) ? W2 : (z == 3) ? W3 : W4;
    if (z < 2) sc = qscale;
  }
  float4 v = ((const float4*)src)[idx];
  ushort4 o;
  o.x = f2b(v.x * sc); o.y = f2b(v.y * sc);
  o.z = f2b(v.z * sc); o.w = f2b(v.w * sc);
  ((ushort4*)dst)[idx] = o;
}

// out = X @ W^T for 5 weights (z). z<4 -> row-major bf16 [4096][768];
// z==4 -> V transposed per head: Vt[b][h][dh][s].
// m97-style staging: global_load_lds width 16, natural [128][64] LDS layout.
__global__ __launch_bounds__(256) void proj_kernel(
    const unsigned short* __restrict__ Xb, const unsigned short* __restrict__ Wb,
    unsigned short* __restrict__ QK, unsigned short* __restrict__ Vt) {
  __shared__ __align__(16) unsigned short Xs[128 * 64];
  __shared__ __align__(16) unsigned short Ws[128 * 64];
  const int z = blockIdx.z;
  const int m0 = blockIdx.y * 128;
  const int n0 = blockIdx.x * 128;
  const unsigned short* Wz = Wb + z * 589824;
  const int tid = threadIdx.x;
  const int lane = tid & 63;
  const int w = tid >> 6;
  const int wm = (w >> 1) * 64;
  const int wn = (w & 1) * 64;
  const int col = lane & 15, quad = lane >> 4;

  // staging: wave w covers rows [w*32, w*32+32), 8 rows per instruction
  const unsigned short* gx = Xb + (m0 + w * 32 + (lane >> 3)) * ND + (lane & 7) * 8;
  const unsigned short* gw = Wz + (n0 + w * 32 + (lane >> 3)) * ND + (lane & 7) * 8;
  unsigned short* lx = Xs + (w * 32) * 64;
  unsigned short* lw = Ws + (w * 32) * 64;

  f32x4 acc[4][4] = {};

  for (int k0 = 0; k0 < 12; k0++) {
    __syncthreads();
#pragma unroll
    for (int i = 0; i < 4; i++) {
      gl_lds16(gx + i * 8 * ND, lx + i * 8 * 64);
      gl_lds16(gw + i * 8 * ND, lw + i * 8 * 64);
    }
    gx += 64;
    gw += 64;
    __syncthreads();
#pragma unroll
    for (int ks = 0; ks < 2; ks++) {
      bf16x8 af[4], bw[4];
#pragma unroll
      for (int t = 0; t < 4; t++) {
        af[t] = *(const bf16x8*)(Xs + (wm + t * 16 + col) * 64 + ks * 32 + quad * 8);
        bw[t] = *(const bf16x8*)(Ws + (wn + t * 16 + col) * 64 + ks * 32 + quad * 8);
      }
#pragma unroll
      for (int mt = 0; mt < 4; mt++)
#pragma unroll
        for (int nt = 0; nt < 4; nt++)
          acc[mt][nt] = MFMA16(af[mt], bw[nt], acc[mt][nt]);
    }
  }

  if (z < 4) {
    unsigned short* out = QK + z * (MTOK * ND);
#pragma unroll
    for (int mt = 0; mt < 4; mt++) {
      int row0 = m0 + wm + mt * 16 + quad * 4;
#pragma unroll
      for (int nt = 0; nt < 4; nt++) {
        int c = n0 + wn + nt * 16 + col;
#pragma unroll
        for (int r = 0; r < 4; r++) out[(row0 + r) * ND + c] = f2b(acc[mt][nt][r]);
      }
    }
  } else {
#pragma unroll
    for (int mt = 0; mt < 4; mt++) {
      int tok = m0 + wm + mt * 16 + quad * 4;
      int b = tok >> 11, s = tok & 2047;
#pragma unroll
      for (int nt = 0; nt < 4; nt++) {
        int c = n0 + wn + nt * 16 + col;
        int h = c >> 6, dh = c & 63;
        ushort4 pk;
        pk.x = f2b(acc[mt][nt][0]);
        pk.y = f2b(acc[mt][nt][1]);
        pk.z = f2b(acc[mt][nt][2]);
        pk.w = f2b(acc[mt][nt][3]);
        *(ushort4*)(Vt + (((b * NH + h) * DHD + dh) * NS + s)) = pk;
      }
    }
  }
}

// Flash attention, scores transposed (S^T = K Q^T), complex magnitude variant.
// No online max (scores bounded; exp2 domain folded into Q scale).
// LDS XOR-swizzled at 16B granularity. Optional split-K (nsplit=2):
// writes unnormalized fp32 partial O + partial l; combine_kernel merges.
__global__ __launch_bounds__(256) void attn_kernel(
    const unsigned short* __restrict__ QK, const unsigned short* __restrict__ Vt,
    float* __restrict__ outp, float* __restrict__ PO, float* __restrict__ PL,
    int nsplit) {
  __shared__ __align__(16) unsigned short Krs[4096];
  __shared__ __align__(16) unsigned short Kis[4096];
  __shared__ __align__(16) unsigned short Vts[4096];
  __shared__ __align__(16) unsigned short Ps[4096];

  const int qt = blockIdx.x;
  const int h = blockIdx.y;
  int b, split, kts;
  if (nsplit == 2) {
    b = blockIdx.z >> 1; split = blockIdx.z & 1; kts = 16;
  } else {
    b = blockIdx.z; split = 0; kts = 32;
  }
  const int kt_begin = split * kts;
  const int tid = threadIdx.x, lane = tid & 63, w = tid >> 6;
  const int col = lane & 15, quad = lane >> 4;
  const int c7 = col & 7;
  const int jb = quad ^ c7;
  const int f0 = jb * 8, f1 = (jb ^ 4) * 8;  // swizzled fragment offsets (ushorts)

  const unsigned short* Qr = QK;
  const unsigned short* Qi = QK + MTOK * ND;
  const unsigned short* Krp = QK + 2 * MTOK * ND;
  const unsigned short* Kip = QK + 3 * MTOK * ND;

  const int q_tok = b * NS + qt * 64 + w * 16 + col;
  const int qoff = q_tok * ND + h * DHD;

  bf16x8 qrf[2], qif[2], qrn[2];
#pragma unroll
  for (int kk = 0; kk < 2; kk++) {
    qrf[kk] = *(const bf16x8*)(Qr + qoff + kk * 32 + quad * 8);
    qif[kk] = *(const bf16x8*)(Qi + qoff + kk * 32 + quad * 8);
    qrn[kk] = qrf[kk] ^ (short)0x8000;  // -Qr
  }

  const int r0 = tid >> 3;
  const int j0 = tid & 7;
  const int dst0 = r0 * 64 + ((j0 ^ (r0 & 7)) * 8);

  const unsigned short* pKr = Krp + (b * NS + kt_begin * 64 + r0) * ND + h * DHD + j0 * 8;
  const unsigned short* pKi = Kip + (b * NS + kt_begin * 64 + r0) * ND + h * DHD + j0 * 8;
  const unsigned short* pV = Vt + (b * NH + h) * (DHD * NS) + r0 * NS + kt_begin * 64 + j0 * 8;

  unsigned short* PsW = Ps + w * 1024;

  f32x4 o[4] = {};
  float lrow = 0.f;

  for (int kt = 0; kt < kts; kt++) {
    __syncthreads();
    *(uint4*)(Krs + dst0) = *(const uint4*)pKr;
    *(uint4*)(Krs + dst0 + 2048) = *(const uint4*)(pKr + 32 * ND);
    *(uint4*)(Kis + dst0) = *(const uint4*)pKi;
    *(uint4*)(Kis + dst0 + 2048) = *(const uint4*)(pKi + 32 * ND);
    *(uint4*)(Vts + dst0) = *(const uint4*)pV;
    *(uint4*)(Vts + dst0 + 2048) = *(const uint4*)(pV + 32 * NS);
    pKr += 64 * ND;
    pKi += 64 * ND;
    pV += 64;
    __syncthreads();

#pragma unroll
    for (int mt = 0; mt < 4; mt++) {
      f32x4 sr = {}, si = {};
      const int rowb = (mt * 16 + col) * 64;
      bf16x8 kr0 = *(const bf16x8*)(Krs + rowb + f0);
      bf16x8 ki0 = *(const bf16x8*)(Kis + rowb + f0);
      bf16x8 kr1 = *(const bf16x8*)(Krs + rowb + f1);
      bf16x8 ki1 = *(const bf16x8*)(Kis + rowb + f1);
      sr = MFMA16(kr0, qrf[0], sr);
      sr = MFMA16(ki0, qif[0], sr);
      si = MFMA16(kr0, qif[0], si);
      si = MFMA16(ki0, qrn[0], si);
      sr = MFMA16(kr1, qrf[1], sr);
      sr = MFMA16(ki1, qif[1], sr);
      si = MFMA16(kr1, qif[1], si);
      si = MFMA16(ki1, qrn[1], si);

      float e0 = __builtin_amdgcn_exp2f(__builtin_amdgcn_sqrtf(sr[0] * sr[0] + si[0] * si[0]));
      float e1 = __builtin_amdgcn_exp2f(__builtin_amdgcn_sqrtf(sr[1] * sr[1] + si[1] * si[1]));
      float e2 = __builtin_amdgcn_exp2f(__builtin_amdgcn_sqrtf(sr[2] * sr[2] + si[2] * si[2]));
      float e3 = __builtin_amdgcn_exp2f(__builtin_amdgcn_sqrtf(sr[3] * sr[3] + si[3] * si[3]));
      lrow += (e0 + e1) + (e2 + e3);
      uint2 pk;
      pk.x = pack2(e0, e1);
      pk.y = pack2(e2, e3);
      *(uint2*)(PsW + col * 64 + (((mt * 2 + (quad >> 1)) ^ c7) * 8) + (quad & 1) * 4) = pk;
    }
    asm volatile("s_waitcnt lgkmcnt(0)" ::: "memory");

    bf16x8 pb0 = *(const bf16x8*)(PsW + col * 64 + f0);
    bf16x8 pb1 = *(const bf16x8*)(PsW + col * 64 + f1);
#pragma unroll
    for (int dt = 0; dt < 4; dt++) {
      const int rowv = (dt * 16 + col) * 64;
      bf16x8 va0 = *(const bf16x8*)(Vts + rowv + f0);
      bf16x8 va1 = *(const bf16x8*)(Vts + rowv + f1);
      o[dt] = MFMA16(va0, pb0, o[dt]);
      o[dt] = MFMA16(va1, pb1, o[dt]);
    }
  }

  lrow += __shfl_xor(lrow, 16);
  lrow += __shfl_xor(lrow, 32);

  if (nsplit == 1) {
    float inv_l = 1.0f / lrow;
    float* op = outp + (size_t)q_tok * ND + h * DHD;
#pragma unroll
    for (int dt = 0; dt < 4; dt++) {
      float4 v;
      v.x = o[dt][0] * inv_l;
      v.y = o[dt][1] * inv_l;
      v.z = o[dt][2] * inv_l;
      v.w = o[dt][3] * inv_l;
      *(float4*)(op + dt * 16 + quad * 4) = v;
    }
  } else {
    const int pid = (((b * NH + h) * 32 + qt) << 1) + split;
    float* po = PO + pid * 4096 + (w * 16 + col) * 64;
#pragma unroll
    for (int dt = 0; dt < 4; dt++) {
      float4 v;
      v.x = o[dt][0]; v.y = o[dt][1]; v.z = o[dt][2]; v.w = o[dt][3];
      *(float4*)(po + dt * 16 + quad * 4) = v;
    }
    if (quad == 0) PL[pid * 64 + w * 16 + col] = lrow;
  }
}

// merge the two split-K partials: out = (O0+O1)/(l0+l1)
__global__ void combine_kernel(const float* __restrict__ PO,
                               const float* __restrict__ PL,
                               float* __restrict__ outp) {
  int t = blockIdx.x * blockDim.x + threadIdx.x;  // 786432 threads
  int d4 = t & 15;
  int th = t >> 4;
  int h = th % 12;
  int tok = th / 12;
  int b = tok >> 11, s = tok & 2047;
  int qt = s >> 6, qq = s & 63;
  int pid = (((b * NH + h) * 32 + qt) << 1);
  const float4 a0 = *(const float4*)(PO + (size_t)pid * 4096 + qq * 64 + d4 * 4);
  const float4 a1 = *(const float4*)(PO + (size_t)(pid + 1) * 4096 + qq * 64 + d4 * 4);
  float l = PL[pid * 64 + qq] + PL[(pid + 1) * 64 + qq];
  float inv = 1.0f / l;
  float4 r;
  r.x = (a0.x + a1.x) * inv;
  r.y = (a0.y + a1.y) * inv;
  r.z = (a0.z + a1.z) * inv;
  r.w = (a0.w + a1.w) * inv;
  *(float4*)(outp + (size_t)tok * ND + h * DHD + d4 * 4) = r;
}

extern "C" void kernel_launch(void* const* d_in, const int* in_sizes, int n_in,
                              void* d_out, int out_size, void* d_ws, size_t ws_size,
                              hipStream_t stream) {
  const float* X = (const float*)d_in[0];
  unsigned short* ws = (unsigned short*)d_ws;
  unsigned short* Xb = ws + OFF_XB;
  unsigned short* Wb = ws + OFF_WB;
  unsigned short* QK = ws + OFF_QK;
  unsigned short* Vt = ws + OFF_VT;
  float* PO = (float*)(ws + OFF_PO);
  float* PL = (float*)(ws + OFF_PL);

  const float QSCALE = 0.125f * 1.44269504088896f;  // 1/sqrt(Dh) * log2(e)

  cvt_all<<<5952, 256, 0, stream>>>(X, (const float*)d_in[1], (const float*)d_in[2],
                                    (const float*)d_in[3], (const float*)d_in[4],
                                    (const float*)d_in[5], Xb, Wb, QSCALE);

  proj_kernel<<<dim3(6, 32, 5), 256, 0, stream>>>(Xb, Wb, QK, Vt);

  const int nsplit = (ws_size >= WS_NEED_SPLIT) ? 2 : 1;
  attn_kernel<<<dim3(32, 12, 2 * nsplit), 256, 0, stream>>>(QK, Vt, (float*)d_out,
                                                            PO, PL, nsplit);
  if (nsplit == 2)
    combine_kernel<<<3072, 256, 0, stream>>>(PO, PL, (float*)d_out);
}